// Round 1
// baseline (207.298 us; speedup 1.0000x reference)
//
#include <hip/hip_runtime.h>
#include <hip/hip_bf16.h>

#define B_ 64
#define L_ 2048
#define H_ 128
#define O_ 128
#define N_ 256
#define TC_ 256
#define NCHUNK_ 8
#define NSTRIP_ 16

using f32x4 = __attribute__((ext_vector_type(4))) float;
using s16x8 = __attribute__((ext_vector_type(8))) short;
using i32x4 = __attribute__((ext_vector_type(4))) int;

__device__ __forceinline__ int pack_bf16(float a, float b) {
    // truncate-to-bf16 pack: low 16 = bf16(a), high 16 = bf16(b)
    return (int)((__float_as_uint(a) >> 16) | (__float_as_uint(b) & 0xffff0000u));
}

// ---------------------------------------------------------------------------
// K0: build (gamma*B)^T in bf16 [512 cols][128 h] and complex weight tables.
//   cols 0..255  = gamma[n]*B_re[n][h], cols 256..511 = gamma[n]*B_im[n][h]
//   lamj[n][j]   = lam[n]^(15-j)            (strip-local weights)
//   lam16t[n]    = lam[n]^16                (strip rescale)
//   lamC[c][n]   = lam[n]^(256*(7-c))       (chunk combine rotation)
// ---------------------------------------------------------------------------
__global__ void prep_kernel(const float* __restrict__ nu_log, const float* __restrict__ theta_log,
                            const float* __restrict__ gamma_log, const float* __restrict__ B_re,
                            const float* __restrict__ B_im, unsigned short* __restrict__ B2T,
                            float2* __restrict__ lamj, float2* __restrict__ lam16t,
                            float2* __restrict__ lamC) {
    if (blockIdx.x < 64) {
        #pragma unroll
        for (int i = 0; i < 4; ++i) {
            int idx = blockIdx.x * 1024 + i * 256 + threadIdx.x;
            int col = idx >> 7;
            int h = idx & 127;
            int n = col & (N_ - 1);
            float g = expf(gamma_log[n]);
            float v = (col < N_ ? B_re[n * H_ + h] : B_im[n * H_ + h]) * g;
            unsigned ub = __float_as_uint(v);
            B2T[idx] = (unsigned short)((ub + 0x7fffu + ((ub >> 16) & 1u)) >> 16); // RNE
        }
    } else {
        int n = threadIdx.x;  // 256 threads
        double lnr = -(double)expf(nu_log[n]);   // ln|lam|
        double th = (double)expf(theta_log[n]);  // arg(lam)
        double r = exp(lnr);
        double sn, cs;
        sincos(th, &sn, &cs);
        double lre = r * cs, lim = r * sn;
        double pre = 1.0, pim = 0.0;             // lam^0
        for (int k = 0; k < 16; ++k) {
            lamj[n * 16 + 15 - k] = make_float2((float)pre, (float)pim);
            double t1 = pre * lre - pim * lim;
            double t2 = pre * lim + pim * lre;
            pre = t1; pim = t2;
        }
        lam16t[n] = make_float2((float)pre, (float)pim);   // lam^16
        double wre = pre, wim = pim;
        for (int i = 0; i < 4; ++i) {                      // -> lam^256
            double t1 = wre * wre - wim * wim;
            double t2 = 2.0 * wre * wim;
            wre = t1; wim = t2;
        }
        double are = 1.0, aim = 0.0;
        for (int cc = 7; cc >= 0; --cc) {
            lamC[cc * N_ + n] = make_float2((float)are, (float)aim);
            double t1 = are * wre - aim * wim;
            double t2 = are * wim + aim * wre;
            are = t1; aim = t2;
        }
    }
}

// ---------------------------------------------------------------------------
// K1: per (batch, 256-step chunk) block. 4 waves, each owns 4 n-pairs
// (re-col tile + im-col tile per pair). B-frags in registers (reused over all
// 16 strips), A-frags loaded directly from global u (no LDS, no barriers).
// Per strip: z <- lam16*z + sum_j lam^(15-j)*Bu_j   (z complex per column).
// Epilogue: quad-reduce, rotate by lamC, atomicAdd into X[b][n] (complex).
// ---------------------------------------------------------------------------
__global__ __launch_bounds__(256, 2)
void scan_kernel(const float* __restrict__ u, const unsigned short* __restrict__ B2T,
                 const float2* __restrict__ lamj, const float2* __restrict__ lam16t,
                 const float2* __restrict__ lamC, float* __restrict__ X) {
    const int b = blockIdx.x >> 3;
    const int c = blockIdx.x & 7;
    const int wave = (threadIdx.x >> 6) & 3;
    const int lane = threadIdx.x & 63;
    const int m = lane & 15;
    const int q = lane >> 4;

    s16x8 bf[4][2][4];   // [pair][re/im][k-slice]
    float2 wl[4][4];     // local strip weights lam^(15-(q*4+r))
    float2 l16[4];

    #pragma unroll
    for (int p = 0; p < 4; ++p) {
        const int n = wave * 64 + p * 16 + m;
        #pragma unroll
        for (int part = 0; part < 2; ++part) {
            const unsigned short* rp = B2T + (size_t)(part * N_ + n) * H_ + q * 8;
            #pragma unroll
            for (int sl = 0; sl < 4; ++sl)
                bf[p][part][sl] = *(const s16x8*)(rp + sl * 32);
        }
        #pragma unroll
        for (int r = 0; r < 4; ++r) wl[p][r] = lamj[n * 16 + q * 4 + r];
        l16[p] = lam16t[n];
    }

    float2 zr[4], zi[4];
    #pragma unroll
    for (int p = 0; p < 4; ++p) {
        zr[p] = make_float2(0.f, 0.f);
        zi[p] = make_float2(0.f, 0.f);
    }

    const float* ub = u + ((size_t)b * L_ + (size_t)c * TC_) * H_;

    #pragma unroll 1
    for (int s = 0; s < NSTRIP_; ++s) {
        // A fragment source: rows t = s*16+m, k = sl*32 + q*8 + j
        const float* up = ub + (s * 16 + m) * H_ + q * 8;
        float4 ua[8];
        #pragma unroll
        for (int sl = 0; sl < 4; ++sl) {
            ua[2 * sl]     = *(const float4*)(up + sl * 32);
            ua[2 * sl + 1] = *(const float4*)(up + sl * 32 + 4);
        }
        s16x8 afr[4];
        #pragma unroll
        for (int sl = 0; sl < 4; ++sl) {
            i32x4 w;
            w[0] = pack_bf16(ua[2 * sl].x, ua[2 * sl].y);
            w[1] = pack_bf16(ua[2 * sl].z, ua[2 * sl].w);
            w[2] = pack_bf16(ua[2 * sl + 1].x, ua[2 * sl + 1].y);
            w[3] = pack_bf16(ua[2 * sl + 1].z, ua[2 * sl + 1].w);
            afr[sl] = __builtin_bit_cast(s16x8, w);
        }
        // rescale accumulators by lam^16 (complex)
        #pragma unroll
        for (int p = 0; p < 4; ++p) {
            float2 a = zr[p];
            zr[p].x = l16[p].x * a.x - l16[p].y * a.y;
            zr[p].y = l16[p].x * a.y + l16[p].y * a.x;
            float2 bb = zi[p];
            zi[p].x = l16[p].x * bb.x - l16[p].y * bb.y;
            zi[p].y = l16[p].x * bb.y + l16[p].y * bb.x;
        }
        // MFMA + weighted fold. D layout: col=lane&15, row=q*4+r (row = strip-local t)
        #pragma unroll
        for (int p = 0; p < 4; ++p) {
            f32x4 acc = {0.f, 0.f, 0.f, 0.f};
            #pragma unroll
            for (int sl = 0; sl < 4; ++sl)
                acc = __builtin_amdgcn_mfma_f32_16x16x32_bf16(afr[sl], bf[p][0][sl], acc, 0, 0, 0);
            #pragma unroll
            for (int r = 0; r < 4; ++r) {
                zr[p].x += wl[p][r].x * acc[r];
                zr[p].y += wl[p][r].y * acc[r];
            }
            f32x4 acc2 = {0.f, 0.f, 0.f, 0.f};
            #pragma unroll
            for (int sl = 0; sl < 4; ++sl)
                acc2 = __builtin_amdgcn_mfma_f32_16x16x32_bf16(afr[sl], bf[p][1][sl], acc2, 0, 0, 0);
            #pragma unroll
            for (int r = 0; r < 4; ++r) {
                zi[p].x += wl[p][r].x * acc2[r];
                zi[p].y += wl[p][r].y * acc2[r];
            }
        }
    }

    // reduce across the 4 quads (rows were split across lane>>4)
    #pragma unroll
    for (int p = 0; p < 4; ++p) {
        zr[p].x += __shfl_xor(zr[p].x, 16); zr[p].x += __shfl_xor(zr[p].x, 32);
        zr[p].y += __shfl_xor(zr[p].y, 16); zr[p].y += __shfl_xor(zr[p].y, 32);
        zi[p].x += __shfl_xor(zi[p].x, 16); zi[p].x += __shfl_xor(zi[p].x, 32);
        zi[p].y += __shfl_xor(zi[p].y, 16); zi[p].y += __shfl_xor(zi[p].y, 32);
    }

    if (lane < 16) {
        #pragma unroll
        for (int p = 0; p < 4; ++p) {
            const int n = wave * 64 + p * 16 + m;
            float2 lc = lamC[c * N_ + n];
            // x contribution = lamC * (z_re_col + i * z_im_col)
            float prr = lc.x * zr[p].x - lc.y * zr[p].y;
            float pri = lc.x * zr[p].y + lc.y * zr[p].x;
            float pir = lc.x * zi[p].x - lc.y * zi[p].y;
            float pii = lc.x * zi[p].y + lc.y * zi[p].x;
            atomicAdd(&X[(size_t)(b * N_ + n) * 2 + 0], prr - pii);
            atomicAdd(&X[(size_t)(b * N_ + n) * 2 + 1], pri + pir);
        }
    }
}

// ---------------------------------------------------------------------------
// K2: y[b,o] = sum_n (Cre[o,n]*Xre[b,n] - Cim[o,n]*Xim[b,n]) + sum_h D[o,h]*u[b,L-1,h]
// ---------------------------------------------------------------------------
__global__ void out_kernel(const float* __restrict__ X, const float* __restrict__ C_re,
                           const float* __restrict__ C_im, const float* __restrict__ Dm,
                           const float* __restrict__ u, float* __restrict__ out) {
    __shared__ float xre[N_], xim[N_], ul[H_];
    const int b = blockIdx.x;
    const int t = threadIdx.x;
    xre[t] = X[(size_t)(b * N_ + t) * 2 + 0];
    xim[t] = X[(size_t)(b * N_ + t) * 2 + 1];
    if (t < H_) ul[t] = u[((size_t)b * L_ + (L_ - 1)) * H_ + t];
    __syncthreads();
    const int o = t >> 1;
    const int h = t & 1;
    const float* cre = C_re + o * N_ + h * 128;
    const float* cim = C_im + o * N_ + h * 128;
    const float* xr = xre + h * 128;
    const float* xi = xim + h * 128;
    float s = 0.f;
    #pragma unroll 4
    for (int n = 0; n < 128; ++n) s += cre[n] * xr[n] - cim[n] * xi[n];
    const float* dp = Dm + o * H_ + h * 64;
    const float* up = ul + h * 64;
    #pragma unroll 4
    for (int k = 0; k < 64; ++k) s += dp[k] * up[k];
    s += __shfl_xor(s, 1);
    if (h == 0) out[b * O_ + o] = s;
}

extern "C" void kernel_launch(void* const* d_in, const int* in_sizes, int n_in,
                              void* d_out, int out_size, void* d_ws, size_t ws_size,
                              hipStream_t stream) {
    const float* u         = (const float*)d_in[2];   // dynamics_disturbance_time_window
    const float* nu_log    = (const float*)d_in[3];
    const float* theta_log = (const float*)d_in[4];
    const float* gamma_log = (const float*)d_in[5];
    const float* B_re      = (const float*)d_in[6];
    const float* B_im      = (const float*)d_in[7];
    const float* C_re      = (const float*)d_in[8];
    const float* C_im      = (const float*)d_in[9];
    const float* Dm        = (const float*)d_in[10];

    char* ws = (char*)d_ws;
    float*          X      = (float*)ws;                       // 131072 B
    unsigned short* B2T    = (unsigned short*)(ws + 131072);   // 131072 B
    float2*         lamj   = (float2*)(ws + 262144);           // 32768 B
    float2*         lam16t = (float2*)(ws + 294912);           // 2048 B
    float2*         lamC   = (float2*)(ws + 296960);           // 16384 B

    hipMemsetAsync(X, 0, (size_t)B_ * N_ * 2 * sizeof(float), stream);
    prep_kernel<<<65, 256, 0, stream>>>(nu_log, theta_log, gamma_log, B_re, B_im,
                                        B2T, lamj, lam16t, lamC);
    scan_kernel<<<B_ * NCHUNK_, 256, 0, stream>>>(u, B2T, lamj, lam16t, lamC, X);
    out_kernel<<<B_, 256, 0, stream>>>(X, C_re, C_im, Dm, u, (float*)d_out);
}

// Round 2
// 200.805 us; speedup vs baseline: 1.0323x; 1.0323x over previous
//
#include <hip/hip_runtime.h>
#include <hip/hip_bf16.h>
#include <math.h>

#define B_ 64
#define L_ 2048
#define H_ 128
#define O_ 128
#define N_ 256

#define BM_ 64
#define BK_ 32
#define KST_ 64          // K stages = 2048/32
#define NMT_ 8           // 512 rows / BM_
#define BROW_ 40         // Bsm row stride in shorts: 80B rows -> 16B aligned, ~2-way banks

using f32x4 = __attribute__((ext_vector_type(4))) float;
using s16x8 = __attribute__((ext_vector_type(8))) short;
using i32x4 = __attribute__((ext_vector_type(4))) int;

__device__ __forceinline__ int pack_bf16(float a, float b) {
    // low 16 = bf16(a) (truncate), high 16 = bf16(b)
    return (int)((__float_as_uint(a) >> 16) | (__float_as_uint(b) & 0xffff0000u));
}
__device__ __forceinline__ unsigned short bf16_rne(float v) {
    unsigned u = __float_as_uint(v);
    return (unsigned short)((u + 0x7fffu + ((u >> 16) & 1u)) >> 16);
}

// ---------------------------------------------------------------------------
// prep1: block 0: sort modes by decay rate (ascending nu = slowest first),
//        build perm[256] and per-m-tile k-start table ksg[8].
//        blocks 1..64: Bg tables (B*exp(gamma)) fp32 + zero X.
// ---------------------------------------------------------------------------
__global__ void prep1_kernel(const float* __restrict__ nu_log, const float* __restrict__ gamma_log,
                             const float* __restrict__ B_re, const float* __restrict__ B_im,
                             float* __restrict__ X, float* __restrict__ Bgr, float* __restrict__ Bgi,
                             int* __restrict__ perm, int* __restrict__ ksg) {
    if (blockIdx.x == 0) {
        __shared__ float nu_s[N_];
        __shared__ int perm_s[N_];
        const int n = threadIdx.x;
        float nu = expf(nu_log[n]);
        nu_s[n] = nu;
        __syncthreads();
        int rank = 0;
        for (int j = 0; j < N_; ++j) {
            float vj = nu_s[j];
            rank += (vj < nu || (vj == nu && j < n)) ? 1 : 0;
        }
        perm_s[rank] = n;
        __syncthreads();
        perm[n] = perm_s[n];
        if (n < NMT_) {
            // slowest mode in tile = first rank of the tile (32 ranks per 64-row tile)
            float nu0 = nu_s[perm_s[n * 32]];
            float cutoff = 35.0f / nu0;                 // e^-35 ~ 6e-16: safe truncation
            int kst = L_ - 1 - (int)cutoff;
            if (kst < 0) kst = 0;
            ksg[n] = kst >> 5;                          // floor to stage
        }
    } else {
        const int i = (blockIdx.x - 1) * 256 + threadIdx.x;   // 0..16383
        #pragma unroll
        for (int kk = 0; kk < 2; ++kk) {
            int idx = i * 2 + kk;                              // 0..32767
            int n = idx >> 7;
            float g = expf(gamma_log[n]);
            Bgr[idx] = B_re[idx] * g;
            Bgi[idx] = B_im[idx] * g;
        }
        X[i * 2] = 0.f;
        X[i * 2 + 1] = 0.f;
    }
}

// ---------------------------------------------------------------------------
// prep2: Lam[512][2048] bf16.  row = 2*rank + part; n = perm[rank];
//        Lam[row][t] = part==0 ? Re(lam_n^(L-1-t)) : Im(lam_n^(L-1-t))
// ---------------------------------------------------------------------------
__global__ void prep2_kernel(const float* __restrict__ nu_log, const float* __restrict__ theta_log,
                             const int* __restrict__ perm, unsigned short* __restrict__ Lam) {
    const int row = blockIdx.x;
    const int rank = row >> 1, part = row & 1;
    const int n = perm[rank];
    const float nu = expf(nu_log[n]);
    const double th = (double)expf(theta_log[n]);
    const int t0 = threadIdx.x * 8;
    union { unsigned short us[8]; s16x8 v; } w;
    #pragma unroll
    for (int j = 0; j < 8; ++j) {
        int e = L_ - 1 - (t0 + j);
        float mag = expf(-nu * (float)e);               // underflows to 0 for dead tail
        double ang = (double)e * th;
        ang -= floor(ang * (1.0 / 6.283185307179586)) * 6.283185307179586;
        float s, c;
        __sincosf((float)ang, &s, &c);
        w.us[j] = bf16_rne(mag * (part ? s : c));
    }
    *(s16x8*)(Lam + (size_t)row * L_ + t0) = w.v;
}

// ---------------------------------------------------------------------------
// gemm: per (mtile, kchunk, batch) block: G-tile[64 rows][128 h] over its
// K-stage range, LDS double-buffered BK=32. Epilogue folds Bg and atomicAdds
// complex x[b,n] partials (K-split is additive in this formulation).
// ---------------------------------------------------------------------------
__global__ __launch_bounds__(256, 4)
void gemm_kernel(const float* __restrict__ u, const unsigned short* __restrict__ Lam,
                 const float* __restrict__ Bgr, const float* __restrict__ Bgi,
                 const int* __restrict__ perm, const int* __restrict__ ksg,
                 float* __restrict__ X) {
    const int bx = blockIdx.x;
    const int mt = bx >> 7;               // heavy tiles first in grid order
    const int kc = (bx >> 6) & 1;
    const int b  = bx & 63;
    const int tid = threadIdx.x;
    const int wave = tid >> 6, lane = tid & 63;
    const int m16 = lane & 15, q = lane >> 4;

    const int ks = ksg[mt];
    const int S = KST_ - ks;
    const int half = (S + 1) >> 1;
    const int s0 = ks + kc * half;
    const int s1 = (s0 + half < KST_) ? (s0 + half) : KST_;
    if (s0 >= s1) return;

    __shared__ unsigned short Asm[2][BM_ * BK_];    // [(q*64+row)*8 + j]  (k-slice-major)
    __shared__ unsigned short Bsm[2][H_ * BROW_];   // [h*BROW_ + t]       (transposed u, bf16)

    const float* ub = u + (size_t)b * (L_ * H_);
    const unsigned short* Ag = Lam + (size_t)(mt * BM_) * L_;

    // staging coords
    const int qs = tid & 3, rs = tid >> 2;          // A: thread -> (k-slice, row)
    const int hs = tid & 127, tq = tid >> 7;        // B: thread -> (h, t-half)
    const float* ubt = ub + (size_t)tq * 16 * H_ + hs;
    const unsigned short* Agt = Ag + (size_t)rs * L_ + qs * 8;
    unsigned short* AsmW[2] = { &Asm[0][(qs * 64 + rs) * 8], &Asm[1][(qs * 64 + rs) * 8] };
    unsigned short* BsmW[2] = { &Bsm[0][hs * BROW_ + tq * 16], &Bsm[1][hs * BROW_ + tq * 16] };

    f32x4 acc[4][2];
    #pragma unroll
    for (int i = 0; i < 4; ++i)
        #pragma unroll
        for (int jn = 0; jn < 2; ++jn)
            acc[i][jn] = (f32x4){0.f, 0.f, 0.f, 0.f};

    // prologue: stage s0 -> buffer 0
    {
        s16x8 areg = *(const s16x8*)(Agt + (size_t)s0 * BK_);
        float v[16];
        const float* up = ubt + (size_t)s0 * BK_ * H_;
        #pragma unroll
        for (int j = 0; j < 16; ++j) v[j] = up[j * H_];
        *(s16x8*)AsmW[0] = areg;
        i32x4 w0, w1;
        w0[0] = pack_bf16(v[0], v[1]);   w0[1] = pack_bf16(v[2], v[3]);
        w0[2] = pack_bf16(v[4], v[5]);   w0[3] = pack_bf16(v[6], v[7]);
        w1[0] = pack_bf16(v[8], v[9]);   w1[1] = pack_bf16(v[10], v[11]);
        w1[2] = pack_bf16(v[12], v[13]); w1[3] = pack_bf16(v[14], v[15]);
        *(i32x4*)BsmW[0] = w0;
        *(i32x4*)(BsmW[0] + 8) = w1;
    }
    __syncthreads();

    int cur = 0;
    for (int kt = s0; kt < s1; ++kt) {
        const int nxt = kt + 1;
        const bool pf = (nxt < s1);
        s16x8 areg;
        float v[16];
        if (pf) {  // issue next-stage loads early; they fly during compute
            areg = *(const s16x8*)(Agt + (size_t)nxt * BK_);
            const float* up = ubt + (size_t)nxt * BK_ * H_;
            #pragma unroll
            for (int j = 0; j < 16; ++j) v[j] = up[j * H_];
        }
        // compute current stage
        const unsigned short* As = Asm[cur];
        const unsigned short* Bs = Bsm[cur];
        s16x8 afr[4], bfr[2];
        #pragma unroll
        for (int i = 0; i < 4; ++i)
            afr[i] = *(const s16x8*)(As + (q * 64 + i * 16 + m16) * 8);
        #pragma unroll
        for (int jn = 0; jn < 2; ++jn)
            bfr[jn] = *(const s16x8*)(Bs + (wave * 32 + jn * 16 + m16) * BROW_ + q * 8);
        #pragma unroll
        for (int i = 0; i < 4; ++i)
            #pragma unroll
            for (int jn = 0; jn < 2; ++jn)
                acc[i][jn] = __builtin_amdgcn_mfma_f32_16x16x32_bf16(afr[i], bfr[jn], acc[i][jn], 0, 0, 0);
        if (pf) {
            *(s16x8*)AsmW[cur ^ 1] = areg;
            i32x4 w0, w1;
            w0[0] = pack_bf16(v[0], v[1]);   w0[1] = pack_bf16(v[2], v[3]);
            w0[2] = pack_bf16(v[4], v[5]);   w0[3] = pack_bf16(v[6], v[7]);
            w1[0] = pack_bf16(v[8], v[9]);   w1[1] = pack_bf16(v[10], v[11]);
            w1[2] = pack_bf16(v[12], v[13]); w1[3] = pack_bf16(v[14], v[15]);
            *(i32x4*)BsmW[cur ^ 1] = w0;
            *(i32x4*)(BsmW[cur ^ 1] + 8) = w1;
        }
        __syncthreads();
        cur ^= 1;
    }

    // epilogue: fold Bg, reduce over h (16 lanes), atomicAdd complex partials
    #pragma unroll
    for (int i = 0; i < 4; ++i) {
        #pragma unroll
        for (int r = 0; r < 4; ++r) {
            const int row = mt * BM_ + i * 16 + q * 4 + r;
            const int nid = perm[row >> 1];
            const int part = r & 1;            // row&1 == r&1 (re=0 / im=1)
            float xre = 0.f, xim = 0.f;
            #pragma unroll
            for (int jn = 0; jn < 2; ++jn) {
                const int h = wave * 32 + jn * 16 + m16;
                const float g = acc[i][jn][r];
                const float br = Bgr[nid * H_ + h];
                const float bi = Bgi[nid * H_ + h];
                if (part == 0) { xre += br * g; xim += bi * g; }
                else           { xre -= bi * g; xim += br * g; }
            }
            #pragma unroll
            for (int d = 1; d < 16; d <<= 1) {
                xre += __shfl_xor(xre, d);
                xim += __shfl_xor(xim, d);
            }
            if (m16 == 0) {
                atomicAdd(&X[(b * N_ + nid) * 2 + 0], xre);
                atomicAdd(&X[(b * N_ + nid) * 2 + 1], xim);
            }
        }
    }
}

// ---------------------------------------------------------------------------
// out: y[b,o] = sum_n (Cre*Xre - Cim*Xim) + sum_h D[o,h]*u[b,L-1,h]
// ---------------------------------------------------------------------------
__global__ void out_kernel(const float* __restrict__ X, const float* __restrict__ C_re,
                           const float* __restrict__ C_im, const float* __restrict__ Dm,
                           const float* __restrict__ u, float* __restrict__ out) {
    __shared__ float xre[N_], xim[N_], ul[H_];
    const int b = blockIdx.x;
    const int t = threadIdx.x;
    xre[t] = X[(size_t)(b * N_ + t) * 2 + 0];
    xim[t] = X[(size_t)(b * N_ + t) * 2 + 1];
    if (t < H_) ul[t] = u[((size_t)b * L_ + (L_ - 1)) * H_ + t];
    __syncthreads();
    const int o = t >> 1;
    const int h = t & 1;
    const float* cre = C_re + o * N_ + h * 128;
    const float* cim = C_im + o * N_ + h * 128;
    const float* xr = xre + h * 128;
    const float* xi = xim + h * 128;
    float s = 0.f;
    #pragma unroll 4
    for (int n = 0; n < 128; ++n) s += cre[n] * xr[n] - cim[n] * xi[n];
    const float* dp = Dm + o * H_ + h * 64;
    const float* up = ul + h * 64;
    #pragma unroll 4
    for (int k = 0; k < 64; ++k) s += dp[k] * up[k];
    s += __shfl_xor(s, 1);
    if (h == 0) out[b * O_ + o] = s;
}

extern "C" void kernel_launch(void* const* d_in, const int* in_sizes, int n_in,
                              void* d_out, int out_size, void* d_ws, size_t ws_size,
                              hipStream_t stream) {
    const float* u         = (const float*)d_in[2];   // dynamics_disturbance_time_window
    const float* nu_log    = (const float*)d_in[3];
    const float* theta_log = (const float*)d_in[4];
    const float* gamma_log = (const float*)d_in[5];
    const float* B_re      = (const float*)d_in[6];
    const float* B_im      = (const float*)d_in[7];
    const float* C_re      = (const float*)d_in[8];
    const float* C_im      = (const float*)d_in[9];
    const float* Dm        = (const float*)d_in[10];

    char* ws = (char*)d_ws;
    float*          X    = (float*)ws;                         // 131072 B
    unsigned short* Lam  = (unsigned short*)(ws + 131072);     // 2 MiB
    float*          Bgr  = (float*)(ws + 2228224);             // 131072 B
    float*          Bgi  = (float*)(ws + 2359296);             // 131072 B
    int*            perm = (int*)(ws + 2490368);               // 1 KiB
    int*            ksg  = (int*)(ws + 2491392);               // 32 B

    prep1_kernel<<<65, 256, 0, stream>>>(nu_log, gamma_log, B_re, B_im, X, Bgr, Bgi, perm, ksg);
    prep2_kernel<<<512, 256, 0, stream>>>(nu_log, theta_log, perm, Lam);
    gemm_kernel<<<1024, 256, 0, stream>>>(u, Lam, Bgr, Bgi, perm, ksg, X);
    out_kernel<<<B_, 256, 0, stream>>>(X, C_re, C_im, Dm, u, (float*)d_out);
}

// Round 4
// 193.351 us; speedup vs baseline: 1.0721x; 1.0385x over previous
//
#include <hip/hip_runtime.h>
#include <hip/hip_bf16.h>
#include <math.h>
#include <stdint.h>

#define B_ 64
#define L_ 2048
#define H_ 128
#define O_ 128
#define N_ 256
#define CH_ 128      // timesteps per chunk
#define NCH_ 16      // chunks
#define SPC_ 8       // strips (16 t) per chunk

using f32x4 = __attribute__((ext_vector_type(4))) float;
using i32x4 = __attribute__((ext_vector_type(4))) int;
using h16x8 = __attribute__((ext_vector_type(8))) _Float16;

__device__ __forceinline__ unsigned short f16_bits(float v) {
    _Float16 h = (_Float16)v;                 // RNE convert
    return __builtin_bit_cast(unsigned short, h);
}
__device__ __forceinline__ int pack_f16(float a, float b) {
    return (int)((unsigned)f16_bits(a) | ((unsigned)f16_bits(b) << 16));
}

// ---------------------------------------------------------------------------
// prep: every block self-computes the nu-sorted permutation (rank 0 = slowest
// decay), then fills its slice of: B2Tr (fp16 (gamma*B)^T, rank-ordered cols),
// lamjR[rank][j]=lam^(15-j), lam16R=lam^16, lamCCr[c][rank]=lam^(128*(15-c)),
// nuR, perm, and zeroes X.
// ---------------------------------------------------------------------------
__global__ void prep_kernel(const float* __restrict__ nu_log, const float* __restrict__ theta_log,
                            const float* __restrict__ gamma_log, const float* __restrict__ B_re,
                            const float* __restrict__ B_im, unsigned short* __restrict__ B2Tr,
                            float2* __restrict__ lamjR, float2* __restrict__ lam16R,
                            float2* __restrict__ lamCCr, float* __restrict__ nuR,
                            int* __restrict__ perm, float* __restrict__ X) {
    __shared__ float nu_s[N_];
    __shared__ int perm_s[N_];
    const int t = threadIdx.x;
    float nu = expf(nu_log[t]);
    nu_s[t] = nu;
    __syncthreads();
    {
        int rank = 0;
        for (int j = 0; j < N_; ++j) {
            float vj = nu_s[j];
            rank += (vj < nu || (vj == nu && j < t)) ? 1 : 0;
        }
        perm_s[rank] = t;
    }
    __syncthreads();
    const int bb = blockIdx.x;
    if (bb < 64) {
        #pragma unroll
        for (int kk = 0; kk < 4; ++kk) {
            int e = bb * 1024 + kk * 256 + t;       // 0..65535
            int part = e >> 15, rank = (e >> 7) & 255, h = e & 127;
            int n = perm_s[rank];
            float g = expf(gamma_log[n]);
            float v = (part ? B_im : B_re)[n * H_ + h] * g;
            B2Tr[e] = f16_bits(v);
        }
    } else if (bb == 64) {
        int r = t, n = perm_s[r];
        float nun = nu_s[n];
        double th = (double)expf(theta_log[n]);
        double rr = exp(-(double)nun);
        double sn, cs;
        sincos(th, &sn, &cs);
        double lre = rr * cs, lim = rr * sn;
        double pre = 1.0, pim = 0.0;
        for (int k = 0; k < 16; ++k) {
            lamjR[r * 16 + 15 - k] = make_float2((float)pre, (float)pim);
            double t1 = pre * lre - pim * lim, t2 = pre * lim + pim * lre;
            pre = t1; pim = t2;
        }
        lam16R[r] = make_float2((float)pre, (float)pim);   // lam^16
        nuR[r] = nun;
        perm[r] = n;
        double wre = pre, wim = pim;                        // -> lam^128
        for (int i = 0; i < 3; ++i) {
            double a = wre * wre - wim * wim, b2 = 2.0 * wre * wim;
            wre = a; wim = b2;
        }
        double are = 1.0, aim = 0.0;
        for (int c = 15; c >= 0; --c) {
            lamCCr[c * N_ + r] = make_float2((float)are, (float)aim);
            double a = are * wre - aim * wim, b2 = are * wim + aim * wre;
            are = a; aim = b2;
        }
    } else {
        int idx = (bb - 65) * 1024 + t * 4;                 // 32 blocks x 1024 floats
        f32x4 z = {0.f, 0.f, 0.f, 0.f};
        *(f32x4*)&X[idx] = z;
    }
}

// ---------------------------------------------------------------------------
// scan: 256-thr block = (b, chunk c, half). 4 waves; wave w owns group
// g = half*4 + w (32 ranks = 2 pairs). u strips (16t x 128h) staged
// cooperatively into fp16 LDS (double-buffered, XOR-swizzled 16B units,
// one __syncthreads per strip, next strip's global loads issued before
// compute). z <- lam^16 z + sum_j lam^(15-j) Bu_j per strip; pairs start at
// decay-derived strips; epilogue rotates by lamCC, atomicAdds complex x.
// ---------------------------------------------------------------------------
__global__ __launch_bounds__(256, 2)
void scan_kernel(const float* __restrict__ u, const unsigned short* __restrict__ B2Tr,
                 const float2* __restrict__ lamjR, const float2* __restrict__ lam16R,
                 const float2* __restrict__ lamCCr, const float* __restrict__ nuR,
                 const int* __restrict__ perm, float* __restrict__ X) {
    const int half = blockIdx.x & 1;
    const int c = (blockIdx.x >> 1) & 15;
    const int b = (int)(blockIdx.x >> 5);
    const int tid = threadIdx.x;
    const int wave = tid >> 6, lane = tid & 63;
    const int m = lane & 15, q = lane >> 4;
    const int g = half * 4 + wave;

    // strip alive iff nu*(base_e - 16s) <= 35  (e^-35 ~ 6e-16 truncation)
    const float base_e = 2032.0f - 128.0f * (float)c;
    int sblk = (int)ceilf((base_e - 35.0f / nuR[half * 128]) * 0.0625f);
    if (sblk >= SPC_) return;                 // whole block dead (uniform)
    if (sblk < 0) sblk = 0;
    int sp0 = (int)ceilf((base_e - 35.0f / nuR[g * 32]) * 0.0625f);
    if (sp0 < 0) sp0 = 0;
    int sp1 = (int)ceilf((base_e - 35.0f / nuR[g * 32 + 16]) * 0.0625f);
    if (sp1 < 0) sp1 = 0;                     // sp0/sp1 may be >= SPC_ (dead pair)

    __shared__ __align__(16) unsigned short ubuf[2][16 * 128];   // fp16, 2 x 4 KB

    // B fragments (fp16) + fold weights (fp32), reused over all strips
    h16x8 bf[2][2][4];
    float2 wl[2][4];
    float2 l16[2];
    #pragma unroll
    for (int p = 0; p < 2; ++p) {
        const int rank = g * 32 + p * 16 + m;
        #pragma unroll
        for (int part = 0; part < 2; ++part) {
            const unsigned short* rp = B2Tr + (size_t)(part * N_ + rank) * H_ + q * 8;
            #pragma unroll
            for (int sl = 0; sl < 4; ++sl)
                bf[p][part][sl] = *(const h16x8*)(rp + sl * 32);
        }
        #pragma unroll
        for (int r = 0; r < 4; ++r) wl[p][r] = lamjR[rank * 16 + q * 4 + r];
        l16[p] = lam16R[rank];
    }

    float2 zr[2], zi[2];
    #pragma unroll
    for (int p = 0; p < 2; ++p) { zr[p] = make_float2(0.f, 0.f); zi[p] = make_float2(0.f, 0.f); }

    // staging coords: thread t -> row sr (0..15), 8-float unit sg (0..15)
    const int sr = tid >> 4, sg = tid & 15;
    const float* gsrc = u + ((size_t)b * L_ + (size_t)c * CH_) * H_;
    const float* gstage = gsrc + (size_t)sr * H_ + sg * 8;
    unsigned short* lwr = &ubuf[0][0] + sr * 128 + ((sg ^ sr) * 8);   // swizzled unit
    const int bufStride = 16 * 128;

    // prologue: stage strip sblk -> buf[sblk&1]
    {
        const float* p4 = gstage + (size_t)sblk * 16 * H_;
        float4 a = *(const float4*)p4, b4 = *(const float4*)(p4 + 4);
        i32x4 w;
        w[0] = pack_f16(a.x, a.y);  w[1] = pack_f16(a.z, a.w);
        w[2] = pack_f16(b4.x, b4.y); w[3] = pack_f16(b4.z, b4.w);
        *(i32x4*)(lwr + (sblk & 1) * bufStride) = w;
    }
    __syncthreads();

    for (int s = sblk; s < SPC_; ++s) {
        const bool pf = (s + 1 < SPC_);
        float4 a, b4;
        if (pf) {   // issue next strip's global loads before compute
            const float* p4 = gstage + (size_t)(s + 1) * 16 * H_;
            a = *(const float4*)p4;
            b4 = *(const float4*)(p4 + 4);
        }

        // A fragments from LDS: lane (m,q) wants halves k = sl*32+q*8..+7 of row m
        const unsigned short* lb = &ubuf[s & 1][0];
        h16x8 afr[4];
        #pragma unroll
        for (int sl = 0; sl < 4; ++sl) {
            const int unit = (sl * 4 + q) ^ m;   // matches writer swizzle (r&15 == m)
            afr[sl] = *(const h16x8*)(lb + m * 128 + unit * 8);
        }

        #pragma unroll
        for (int p = 0; p < 2; ++p) {
            const int sp = p ? sp1 : sp0;
            if (s < sp) continue;                 // wave-uniform
            // rescale accumulators by lam^16
            float2 t0 = zr[p];
            zr[p].x = l16[p].x * t0.x - l16[p].y * t0.y;
            zr[p].y = l16[p].x * t0.y + l16[p].y * t0.x;
            float2 t1 = zi[p];
            zi[p].x = l16[p].x * t1.x - l16[p].y * t1.y;
            zi[p].y = l16[p].x * t1.y + l16[p].y * t1.x;
            f32x4 acc = {0.f, 0.f, 0.f, 0.f};
            #pragma unroll
            for (int sl = 0; sl < 4; ++sl)
                acc = __builtin_amdgcn_mfma_f32_16x16x32_f16(afr[sl], bf[p][0][sl], acc, 0, 0, 0);
            #pragma unroll
            for (int r = 0; r < 4; ++r) {
                zr[p].x += wl[p][r].x * acc[r];
                zr[p].y += wl[p][r].y * acc[r];
            }
            f32x4 acc2 = {0.f, 0.f, 0.f, 0.f};
            #pragma unroll
            for (int sl = 0; sl < 4; ++sl)
                acc2 = __builtin_amdgcn_mfma_f32_16x16x32_f16(afr[sl], bf[p][1][sl], acc2, 0, 0, 0);
            #pragma unroll
            for (int r = 0; r < 4; ++r) {
                zi[p].x += wl[p][r].x * acc2[r];
                zi[p].y += wl[p][r].y * acc2[r];
            }
        }

        if (pf) {
            i32x4 w;
            w[0] = pack_f16(a.x, a.y);  w[1] = pack_f16(a.z, a.w);
            w[2] = pack_f16(b4.x, b4.y); w[3] = pack_f16(b4.z, b4.w);
            *(i32x4*)(lwr + ((s + 1) & 1) * bufStride) = w;
        }
        __syncthreads();
    }

    // epilogue: reduce over q, rotate by lamCC, atomic complex partials
    #pragma unroll
    for (int p = 0; p < 2; ++p) {
        const int sp = p ? sp1 : sp0;
        if (sp >= SPC_) continue;                 // pair never ran
        float a = zr[p].x, b2 = zr[p].y, c2 = zi[p].x, d2 = zi[p].y;
        a  += __shfl_xor(a, 16);  a  += __shfl_xor(a, 32);
        b2 += __shfl_xor(b2, 16); b2 += __shfl_xor(b2, 32);
        c2 += __shfl_xor(c2, 16); c2 += __shfl_xor(c2, 32);
        d2 += __shfl_xor(d2, 16); d2 += __shfl_xor(d2, 32);
        if (lane < 16) {
            const int rank = g * 32 + p * 16 + m;
            const int n = perm[rank];
            float2 lc = lamCCr[c * N_ + rank];
            float prr = lc.x * a - lc.y * b2;
            float pri = lc.x * b2 + lc.y * a;
            float pir = lc.x * c2 - lc.y * d2;
            float pii = lc.x * d2 + lc.y * c2;
            atomicAdd(&X[(size_t)(b * N_ + n) * 2 + 0], prr - pii);
            atomicAdd(&X[(size_t)(b * N_ + n) * 2 + 1], pri + pir);
        }
    }
}

// ---------------------------------------------------------------------------
// out: y[b,o] = sum_n (Cre*Xre - Cim*Xim) + sum_h D[o,h]*u[b,L-1,h]
// ---------------------------------------------------------------------------
__global__ void out_kernel(const float* __restrict__ X, const float* __restrict__ C_re,
                           const float* __restrict__ C_im, const float* __restrict__ Dm,
                           const float* __restrict__ u, float* __restrict__ out) {
    __shared__ float xre[N_], xim[N_], ul[H_];
    const int b = blockIdx.x;
    const int t = threadIdx.x;
    xre[t] = X[(size_t)(b * N_ + t) * 2 + 0];
    xim[t] = X[(size_t)(b * N_ + t) * 2 + 1];
    if (t < H_) ul[t] = u[((size_t)b * L_ + (L_ - 1)) * H_ + t];
    __syncthreads();
    const int o = t >> 1;
    const int h = t & 1;
    const float* cre = C_re + o * N_ + h * 128;
    const float* cim = C_im + o * N_ + h * 128;
    const float* xr = xre + h * 128;
    const float* xi = xim + h * 128;
    float s = 0.f;
    #pragma unroll 4
    for (int n = 0; n < 128; ++n) s += cre[n] * xr[n] - cim[n] * xi[n];
    const float* dp = Dm + o * H_ + h * 64;
    const float* up = ul + h * 64;
    #pragma unroll 4
    for (int k = 0; k < 64; ++k) s += dp[k] * up[k];
    s += __shfl_xor(s, 1);
    if (h == 0) out[b * O_ + o] = s;
}

extern "C" void kernel_launch(void* const* d_in, const int* in_sizes, int n_in,
                              void* d_out, int out_size, void* d_ws, size_t ws_size,
                              hipStream_t stream) {
    const float* u         = (const float*)d_in[2];   // dynamics_disturbance_time_window
    const float* nu_log    = (const float*)d_in[3];
    const float* theta_log = (const float*)d_in[4];
    const float* gamma_log = (const float*)d_in[5];
    const float* B_re      = (const float*)d_in[6];
    const float* B_im      = (const float*)d_in[7];
    const float* C_re      = (const float*)d_in[8];
    const float* C_im      = (const float*)d_in[9];
    const float* Dm        = (const float*)d_in[10];

    char* ws = (char*)d_ws;
    float*          X      = (float*)ws;                       // 131072 B
    unsigned short* B2Tr   = (unsigned short*)(ws + 131072);   // 131072 B
    float2*         lamjR  = (float2*)(ws + 262144);           // 32768 B
    float2*         lam16R = (float2*)(ws + 294912);           // 2048 B
    float2*         lamCCr = (float2*)(ws + 296960);           // 32768 B
    float*          nuR    = (float*)(ws + 329728);            // 1024 B
    int*            perm   = (int*)(ws + 330752);              // 1024 B

    prep_kernel<<<97, 256, 0, stream>>>(nu_log, theta_log, gamma_log, B_re, B_im,
                                        B2Tr, lamjR, lam16R, lamCCr, nuR, perm, X);
    scan_kernel<<<B_ * NCH_ * 2, 256, 0, stream>>>(u, B2Tr, lamjR, lam16R, lamCCr, nuR, perm, X);
    out_kernel<<<B_, 256, 0, stream>>>(X, C_re, C_im, Dm, u, (float*)d_out);
}